// Round 1
// baseline (482.614 us; speedup 1.0000x reference)
//
#include <hip/hip_runtime.h>

#define N_SAMP 8192
#define C_DIM 3
#define T_DIM 2048
#define D_DIM (C_DIM * T_DIM)      // 6144 columns
#define K_CLS 10
#define CHUNK 64                   // samples per block
#define NCHUNKS (N_SAMP / CHUNK)   // 128
#define COLS_PER_BLOCK 1024        // 256 threads * 4 floats
#define NGROUPS (D_DIM / COLS_PER_BLOCK)  // 6

// Kernel 1: accumulate per-(class, column) sum and sum-of-squares.
// Thread -> 4 consecutive columns (float4 coalesced); loop over 64 samples.
// y[i] is uniform across the block for a given sample -> readfirstlane makes
// the 10-way class dispatch a scalar branch chain (no VALU predication cost).
__global__ __launch_bounds__(256) void wcss_accum(const float* __restrict__ X,
                                                  const int* __restrict__ y,
                                                  float* __restrict__ S1,
                                                  float* __restrict__ S2) {
    __shared__ int y_lds[CHUNK];
    const int tid = threadIdx.x;
    const int col0 = blockIdx.x * COLS_PER_BLOCK + tid * 4;
    const int i0 = blockIdx.y * CHUNK;

    if (tid < CHUNK) y_lds[tid] = y[i0 + tid];
    __syncthreads();

    float a1[K_CLS][4];
    float a2[K_CLS][4];
#pragma unroll
    for (int k = 0; k < K_CLS; ++k) {
#pragma unroll
        for (int j = 0; j < 4; ++j) { a1[k][j] = 0.0f; a2[k][j] = 0.0f; }
    }

    const float* p = X + (size_t)i0 * D_DIM + col0;
    float4 cur = *(const float4*)p;

#pragma unroll 1
    for (int s = 0; s < CHUNK; ++s) {
        // prefetch next sample's 16B (clamped on last iter)
        const int sn = (s + 1 < CHUNK) ? (s + 1) : s;
        float4 nxt = *(const float4*)(p + (size_t)sn * D_DIM);

        const int yk = __builtin_amdgcn_readfirstlane(y_lds[s]);
        const float qx = cur.x * cur.x, qy = cur.y * cur.y;
        const float qz = cur.z * cur.z, qw = cur.w * cur.w;
#pragma unroll
        for (int k = 0; k < K_CLS; ++k) {
            if (yk == k) {   // scalar compare -> uniform branch
                a1[k][0] += cur.x; a1[k][1] += cur.y;
                a1[k][2] += cur.z; a1[k][3] += cur.w;
                a2[k][0] += qx;    a2[k][1] += qy;
                a2[k][2] += qz;    a2[k][3] += qw;
            }
        }
        cur = nxt;
    }

#pragma unroll
    for (int k = 0; k < K_CLS; ++k) {
        float* b1 = S1 + k * D_DIM + col0;
        float* b2 = S2 + k * D_DIM + col0;
#pragma unroll
        for (int j = 0; j < 4; ++j) {
            atomicAdd(b1 + j, a1[k][j]);
            atomicAdd(b2 + j, a2[k][j]);
        }
    }
}

// Kernel 2: one block per class. Count labels, then sum over D cells of
// S2 - S1^2/cnt, reduce, and add loss_k / (cnt * D * K) into out.
__global__ __launch_bounds__(256) void wcss_finish(const float* __restrict__ S1,
                                                   const float* __restrict__ S2,
                                                   const int* __restrict__ y,
                                                   float* __restrict__ out) {
    const int k = blockIdx.x;
    const int tid = threadIdx.x;
    __shared__ float sbuf[256];

    // count labels == k
    int c = 0;
    for (int i = tid; i < N_SAMP; i += 256) c += (y[i] == k) ? 1 : 0;
    sbuf[tid] = (float)c;
    __syncthreads();
    for (int off = 128; off > 0; off >>= 1) {
        if (tid < off) sbuf[tid] += sbuf[tid + off];
        __syncthreads();
    }
    const float cnt = sbuf[0];
    __syncthreads();

    const float inv_cnt = 1.0f / cnt;
    float t = 0.0f;
    for (int j = tid; j < D_DIM; j += 256) {
        const float s1 = S1[k * D_DIM + j];
        const float s2 = S2[k * D_DIM + j];
        t += s2 - s1 * s1 * inv_cnt;
    }
    sbuf[tid] = t;
    __syncthreads();
    for (int off = 128; off > 0; off >>= 1) {
        if (tid < off) sbuf[tid] += sbuf[tid + off];
        __syncthreads();
    }
    if (tid == 0) {
        const float loss_k = sbuf[0] / (cnt * (float)D_DIM);
        atomicAdd(out, loss_k / (float)K_CLS);
    }
}

extern "C" void kernel_launch(void* const* d_in, const int* in_sizes, int n_in,
                              void* d_out, int out_size, void* d_ws, size_t ws_size,
                              hipStream_t stream) {
    const float* X = (const float*)d_in[0];
    const int* y = (const int*)d_in[1];
    float* S1 = (float*)d_ws;
    float* S2 = S1 + K_CLS * D_DIM;
    float* out = (float*)d_out;

    hipMemsetAsync(d_ws, 0, 2 * K_CLS * D_DIM * sizeof(float), stream);
    hipMemsetAsync(d_out, 0, sizeof(float), stream);

    dim3 grid(NGROUPS, NCHUNKS);
    wcss_accum<<<grid, dim3(256), 0, stream>>>(X, y, S1, S2);
    wcss_finish<<<dim3(K_CLS), dim3(256), 0, stream>>>(S1, S2, y, out);
}

// Round 2
// 347.203 us; speedup vs baseline: 1.3900x; 1.3900x over previous
//
#include <hip/hip_runtime.h>

#define N_SAMP 8192
#define D_DIM 6144
#define K_CLS 10
#define CHUNK 32
#define NCHUNKS (N_SAMP / CHUNK)          // 256
#define COLS_PER_BLOCK 1024               // 256 threads * 4 floats
#define NGROUPS (D_DIM / COLS_PER_BLOCK)  // 6

// Kernel A: bucket sample indices by class (order within class irrelevant).
// One block; 8192 labels, 10 classes. Also writes per-class counts.
__global__ __launch_bounds__(1024) void build_sort(const int* __restrict__ y,
                                                   int* __restrict__ counts,
                                                   int* __restrict__ sorted) {
    __shared__ int lcnt[K_CLS];
    __shared__ int loff[K_CLS];
    const int tid = threadIdx.x;
    if (tid < K_CLS) lcnt[tid] = 0;
    __syncthreads();
    for (int i = tid; i < N_SAMP; i += 1024) atomicAdd(&lcnt[y[i]], 1);
    __syncthreads();
    if (tid == 0) {
        int off = 0;
        for (int k = 0; k < K_CLS; ++k) {
            loff[k] = off; counts[k] = lcnt[k]; off += lcnt[k];
        }
    }
    __syncthreads();
    for (int i = tid; i < N_SAMP; i += 1024) {
        int pos = atomicAdd(&loff[y[i]], 1);
        sorted[pos] = i;
    }
}

// Kernel B: walk class-sorted samples. Per-thread: running S1 float4 (per
// column) + running S2 scalar (column-reduced), flushed on class change
// (wave-uniform scalar branch) and at end. 4-deep load prefetch for MLP.
__global__ __launch_bounds__(256) void wcss_accum(const float* __restrict__ X,
                                                  const int* __restrict__ y,
                                                  const int* __restrict__ sorted,
                                                  float* __restrict__ S1,
                                                  float* __restrict__ s2sum) {
    __shared__ int idx_lds[CHUNK];
    __shared__ int cls_lds[CHUNK];
    const int tid = threadIdx.x;
    const int col0 = blockIdx.x * COLS_PER_BLOCK + tid * 4;
    const int s0g = blockIdx.y * CHUNK;

    if (tid < CHUNK) {
        const int idx = sorted[s0g + tid];
        idx_lds[tid] = idx;
        cls_lds[tid] = y[idx];
    }
    __syncthreads();

    float4 a1 = make_float4(0.f, 0.f, 0.f, 0.f);
    float s2c = 0.f;
    int kcur = __builtin_amdgcn_readfirstlane(cls_lds[0]);

    float4 buf[4];
#pragma unroll
    for (int j = 0; j < 4; ++j)
        buf[j] = *(const float4*)(X + (size_t)idx_lds[j] * D_DIM + col0);

#pragma unroll 1
    for (int s0 = 0; s0 < CHUNK; s0 += 4) {
        float4 nbuf[4];
        const int np = (s0 + 4 < CHUNK) ? (s0 + 4) : (CHUNK - 4);
#pragma unroll
        for (int j = 0; j < 4; ++j)
            nbuf[j] = *(const float4*)(X + (size_t)idx_lds[np + j] * D_DIM + col0);

#pragma unroll
        for (int j = 0; j < 4; ++j) {
            const int yk = __builtin_amdgcn_readfirstlane(cls_lds[s0 + j]);
            if (yk != kcur) {   // uniform branch, rare (class boundary)
                float* b1 = S1 + kcur * D_DIM + col0;
                atomicAdd(b1 + 0, a1.x); atomicAdd(b1 + 1, a1.y);
                atomicAdd(b1 + 2, a1.z); atomicAdd(b1 + 3, a1.w);
                atomicAdd(&s2sum[kcur], s2c);
                a1 = make_float4(0.f, 0.f, 0.f, 0.f);
                s2c = 0.f;
                kcur = yk;
            }
            const float4 v = buf[j];
            a1.x += v.x; a1.y += v.y; a1.z += v.z; a1.w += v.w;
            s2c += v.x * v.x + v.y * v.y + v.z * v.z + v.w * v.w;
        }
#pragma unroll
        for (int j = 0; j < 4; ++j) buf[j] = nbuf[j];
    }

    float* b1 = S1 + kcur * D_DIM + col0;
    atomicAdd(b1 + 0, a1.x); atomicAdd(b1 + 1, a1.y);
    atomicAdd(b1 + 2, a1.z); atomicAdd(b1 + 3, a1.w);
    atomicAdd(&s2sum[kcur], s2c);
}

// Kernel C: 60 blocks (class k × column-slice g). Per cell add
// -S1^2/(cnt^2*D*K); one thread also adds S2sum_k/(cnt*D*K).
__global__ __launch_bounds__(256) void wcss_finish(const float* __restrict__ S1,
                                                   const float* __restrict__ s2sum,
                                                   const int* __restrict__ counts,
                                                   float* __restrict__ out) {
    __shared__ float sbuf[256];
    const int tid = threadIdx.x;
    const int k = blockIdx.x / NGROUPS;
    const int g = blockIdx.x % NGROUPS;
    const float cnt = (float)counts[k];
    const float inv = 1.0f / (cnt * cnt * (float)D_DIM * (float)K_CLS);

    const float4 v = *(const float4*)(S1 + k * D_DIM + g * COLS_PER_BLOCK + tid * 4);
    float t = -(v.x * v.x + v.y * v.y + v.z * v.z + v.w * v.w) * inv;
    if (g == 0 && tid == 0)
        t += s2sum[k] / (cnt * (float)D_DIM * (float)K_CLS);

    sbuf[tid] = t;
    __syncthreads();
    for (int off = 128; off > 0; off >>= 1) {
        if (tid < off) sbuf[tid] += sbuf[tid + off];
        __syncthreads();
    }
    if (tid == 0) atomicAdd(out, sbuf[0]);
}

extern "C" void kernel_launch(void* const* d_in, const int* in_sizes, int n_in,
                              void* d_out, int out_size, void* d_ws, size_t ws_size,
                              hipStream_t stream) {
    const float* X = (const float*)d_in[0];
    const int* y = (const int*)d_in[1];

    float* S1 = (float*)d_ws;                       // K*D floats
    float* s2sum = S1 + K_CLS * D_DIM;              // K floats
    int* counts = (int*)(s2sum + K_CLS);            // K ints
    int* sorted = counts + K_CLS;                   // N ints
    float* out = (float*)d_out;

    hipMemsetAsync(S1, 0, (K_CLS * D_DIM + K_CLS) * sizeof(float), stream);
    hipMemsetAsync(out, 0, sizeof(float), stream);

    build_sort<<<dim3(1), dim3(1024), 0, stream>>>(y, counts, sorted);
    wcss_accum<<<dim3(NGROUPS, NCHUNKS), dim3(256), 0, stream>>>(X, y, sorted, S1, s2sum);
    wcss_finish<<<dim3(K_CLS * NGROUPS), dim3(256), 0, stream>>>(S1, s2sum, counts, out);
}